// Round 16
// baseline (421.842 us; speedup 1.0000x reference)
//
#include <hip/hip_runtime.h>
#include <hip/hip_bf16.h>

typedef __hip_bfloat16 bf16;
typedef unsigned short u16;
typedef unsigned int uint32;
typedef __attribute__((ext_vector_type(8))) short bf16x8;
typedef __attribute__((ext_vector_type(4))) float f32x4;

#define BATCH   128
#define LSIG    128
#define PL      16
#define ST      4
#define WIN     4
#define NPATCH  29
#define NG      (BATCH * NPATCH)   // 3712
#define NNODE   (NG * PL)          // 59392
#define HID     256
#define NCLS    8

// f32 param workspace layout (element offsets)
#define IQ_OFF    0
#define W0A_OFF   32768
#define W0R_OFF   33280
#define B0_OFF    33792
#define BLIN_OFF  34048
#define LNS_OFF   34816
#define LNB_OFF   35840
#define W1T_OFF   36864
#define CB1_OFF   102400
#define CLNS_OFF  102656
#define CLNB_OFF  102912
#define CW2_OFF   103168
#define CB2_OFF   105216
#define CVT_TOTAL 105224
#define WB_TOTAL  393216

#define P_BYTE_OFF   4096
#define WB_BYTE_OFF  425984           // bf16 sage weights: 3 layers x (Wa|Wr) x 65536
#define A_BYTE_OFF   1216512          // bf16 activation buffer in ws (30.4 MB)
#define B_BYTE_OFF   1959936          // bf16 scratch window inside d_out (= emb region)
#define GF_EOFF      (NG * NCLS)                  // 29696
#define EMB_EOFF     (NG * NCLS + NG * HID)       // 979968

#define MFMA_BF16 __builtin_amdgcn_mfma_f32_16x16x32_bf16

__device__ __forceinline__ float b2f(bf16 x) { return __bfloat162float(x); }
__device__ __forceinline__ float lof(uint32 u) { return __uint_as_float(u << 16); }
__device__ __forceinline__ float hif(uint32 u) { return __uint_as_float(u & 0xFFFF0000u); }
__device__ __forceinline__ uint32 packbf(float a, float b) {
  bf16 r0 = __float2bfloat16(a), r1 = __float2bfloat16(b);
  return ((uint32)(*(const u16*)&r1) << 16) | (uint32)(*(const u16*)&r0);
}
__device__ __forceinline__ float ldmix(const void* p, size_t i, int fl) {
  return fl ? ((const float*)p)[i] : __bfloat162float(((const bf16*)p)[i]);
}
// async 16B/lane global->LDS (wave-uniform LDS base, per-lane global addr)
__device__ __forceinline__ void gl_lds16(const uint32* gsrc, uint32* ldst) {
  __builtin_amdgcn_global_load_lds(
      (const __attribute__((address_space(1))) uint32*)gsrc,
      (__attribute__((address_space(3))) uint32*)ldst, 16, 0, 0);
}

// -------- dtype detector --------
__global__ __launch_bounds__(256) void detect_kernel(const u16* __restrict__ iq, int* flag) {
  __shared__ int sbig, snz;
  int t = threadIdx.x;
  if (t == 0) { sbig = 0; snz = 0; }
  __syncthreads();
  int big = 0, nz = 0;
  for (int e = t; e < 16384; e += 256) {
    u16 u = iq[2 * e];
    int ex = (u >> 7) & 0xFF;
    if (ex >= 0xC0) big++;
    if (u != 0) nz++;
  }
  atomicAdd(&sbig, big); atomicAdd(&snz, nz);
  __syncthreads();
  if (t == 0) *flag = (sbig > 4 || snz < 100) ? 1 : 0;   // 1 = f32 inputs
}

// -------- all input conversions: params -> f32 P, sage W -> bf16 WB --------
__global__ __launch_bounds__(256) void convert_all(
    const int* __restrict__ flag,
    const void* iq, const void* w0a, const void* w0r, const void* b0,
    const void* blin, const void* lns, const void* lnb,
    const void* cw1, const void* cb1, const void* clns, const void* clnb,
    const void* cw2, const void* cb2,
    const void* wag, const void* wro,
    float* __restrict__ P, bf16* __restrict__ WB) {
  int idx = blockIdx.x * 256 + threadIdx.x;
  int fl = *flag;
  if (idx < CVT_TOTAL) {
    float v;
    if (idx < W0A_OFF)        v = ldmix(iq,  idx, fl);
    else if (idx < W0R_OFF)   v = ldmix(w0a, idx - W0A_OFF, fl);
    else if (idx < B0_OFF)    v = ldmix(w0r, idx - W0R_OFF, fl);
    else if (idx < BLIN_OFF)  v = ldmix(b0,  idx - B0_OFF, fl);
    else if (idx < LNS_OFF)   v = ldmix(blin, idx - BLIN_OFF, fl);
    else if (idx < LNB_OFF)   v = ldmix(lns, idx - LNS_OFF, fl);
    else if (idx < W1T_OFF)   v = ldmix(lnb, idx - LNB_OFF, fl);
    else if (idx < CB1_OFF) { int t2 = idx - W1T_OFF;
      v = ldmix(cw1, (t2 & 255) * 256 + (t2 >> 8), fl); }
    else if (idx < CLNS_OFF)  v = ldmix(cb1, idx - CB1_OFF, fl);
    else if (idx < CLNB_OFF)  v = ldmix(clns, idx - CLNS_OFF, fl);
    else if (idx < CW2_OFF)   v = ldmix(clnb, idx - CLNB_OFF, fl);
    else if (idx < CB2_OFF)   v = ldmix(cw2, idx - CW2_OFF, fl);
    else                      v = ldmix(cb2, idx - CB2_OFF, fl);
    P[idx] = v;
  } else if (idx < CVT_TOTAL + WB_TOTAL) {
    int k = idx - CVT_TOTAL;
    int l = k >> 17, m = (k >> 16) & 1, r = k & 65535;
    const void* src = m ? wro : wag;
    WB[k] = __float2bfloat16(ldmix(src, l * 65536 + r, fl));
  }
}

// -------- layer 0: patch extract + SAGE(2->256) + LN + ReLU --------
// Output in SWIZZLED global layout (16B slot ^= node&7).
__global__ __launch_bounds__(256) void layer0_kernel(
    const float* __restrict__ P, bf16* __restrict__ hout) {
  int g = blockIdx.x, f = threadIdx.x;
  int b = g / NPATCH, p = g % NPATCH;
  __shared__ float x_s[PL][2];
  __shared__ float xp_s[2];
  __shared__ float agg_s[PL][2];
  __shared__ float o_s[PL][HID];
  __shared__ float mv_s[PL][2];
  if (f < 32) { int j = f & 15, c = f >> 4;
    x_s[j][c] = P[IQ_OFF + (b * 2 + c) * LSIG + p * ST + j]; }
  if (f < 2) xp_s[f] = (p > 0) ? P[IQ_OFF + (b * 2 + f) * LSIG + (p - 1) * ST + PL - 1] : 0.f;
  __syncthreads();
  if (f < 32) { int j = f & 15, c = f >> 4;
    float s = 0.f;
    int lo = j - WIN < 0 ? 0 : j - WIN, hi = j + WIN > 15 ? 15 : j + WIN;
    for (int i = lo; i <= hi; ++i) if (i != j) s += x_s[i][c];
    int deg = (j < WIN ? j : WIN) + ((15 - j) < WIN ? (15 - j) : WIN);
    if (j == 0 && p > 0) { s += xp_s[c]; deg += 1; }
    agg_s[j][c] = s / (float)deg;
  }
  __syncthreads();
  float wa0 = P[W0A_OFF + f * 2], wa1 = P[W0A_OFF + f * 2 + 1];
  float wr0 = P[W0R_OFF + f * 2], wr1 = P[W0R_OFF + f * 2 + 1];
  float bb = P[B0_OFF + f];
#pragma unroll
  for (int j = 0; j < PL; ++j)
    o_s[j][f] = agg_s[j][0] * wa0 + agg_s[j][1] * wa1 + x_s[j][0] * wr0 + x_s[j][1] * wr1 + bb;
  __syncthreads();
  { int j = f >> 4, q = f & 15;
    float s = 0.f, s2 = 0.f;
#pragma unroll
    for (int i = 0; i < 16; ++i) { float v = o_s[j][q + 16 * i]; s += v; s2 += v * v; }
#pragma unroll
    for (int m = 8; m >= 1; m >>= 1) { s += __shfl_xor(s, m); s2 += __shfl_xor(s2, m); }
    if (q == 0) { float mean = s * (1.f / HID);
      float var = s2 * (1.f / HID) - mean * mean;
      mv_s[j][0] = mean; mv_s[j][1] = rsqrtf(var + 1e-5f); }
  }
  __syncthreads();
  float gl = P[LNS_OFF + f], bl = P[LNB_OFF + f];
#pragma unroll
  for (int j = 0; j < PL; ++j) {
    float v = (o_s[j][f] - mv_s[j][0]) * mv_s[j][1] * gl + bl;
    v = v > 0.f ? v : 0.f;
    bf16 x = __float2bfloat16(v);
    ((u16*)hout)[(size_t)(g * PL + j) * 256 + ((((f >> 3) ^ (j & 7))) << 3) + (f & 7)] = *(const u16*)&x;
  }
}

// ======== BP=8 SAGE layer (non-LAST): 512 thr, 64KB single buffer ========
// Wave w owns rows w*16..w*16+15 x ALL 256 cols (acc[16]).
// GEMM1 h@Wr -> in-place agg -> GEMM2 agg@Wa. LN stats fully in-register
// (row lives inside one 16-lane group). Residual/output via global (swizzled).
__global__ __launch_bounds__(512, 2) void sage_bp8(
    const bf16* __restrict__ hin,
    const bf16* __restrict__ Wa, const bf16* __restrict__ Wr,
    const float* __restrict__ bias,
    const float* __restrict__ lng, const float* __restrict__ lnb,
    bf16* __restrict__ hout) {
  int t = threadIdx.x;
  int w = t >> 6, l = t & 63, lr = l & 15, lg = l >> 4;
  int g0 = blockIdx.x * 8;
  size_t nbase = (size_t)g0 * PL;
  __shared__ uint32 hb[128 * 128];          // 64 KB exactly
  const uint32* hinw = (const uint32*)hin;

  // ---- stage: pre-swizzled global -> linear LDS (async) ----
  const uint32* hg = hinw + nbase * 128;
#pragma unroll
  for (int it = 0; it < 8; ++it) {
    int off = (it * 8 + w) * 256;
    gl_lds16(hg + off + (l << 2), &hb[off]);
  }
  __syncthreads();

  int rowbase = w * 16;
  const bf16* wrB = Wr + lr * HID + lg * 8;
  const bf16* waB = Wa + lr * HID + lg * 8;

  // ---- GEMM1: acc[nt] = h @ Wr^T ----
  f32x4 acc[16];
#pragma unroll
  for (int n = 0; n < 16; ++n) acc[n] = (f32x4){0.f, 0.f, 0.f, 0.f};
  __builtin_amdgcn_s_setprio(1);
#pragma unroll
  for (int ks = 0; ks < 8; ++ks) {
    bf16x8 hf = *(const bf16x8*)&hb[(rowbase + lr) * 128 + (((ks * 4 + lg) ^ (lr & 7)) << 2)];
#pragma unroll
    for (int nt = 0; nt < 16; ++nt) {
      bf16x8 wf = *(const bf16x8*)(wrB + nt * 16 * HID + ks * 32);
      acc[nt] = MFMA_BF16(hf, wf, acc[nt], 0, 0, 0);
    }
  }
  __builtin_amdgcn_s_setprio(0);

  // ---- boundary pre-read (before in-place writes) ----
  int c2 = t & 127, pg = t >> 7;          // 4 groups x 2 patches
  uint32 bnd[2];
#pragma unroll
  for (int pi2 = 0; pi2 < 2; ++pi2) {
    int pi = pg * 2 + pi2;
    int hp = ((g0 + pi) % NPATCH) != 0;
    uint32 u = 0;
    if (hp) {
      if (pi == 0) u = hinw[(nbase - 1) * 128 + (((c2 >> 2) ^ 7) << 2) + (c2 & 3)];
      else { int br = pi * 16 - 1;        // br&7 == 7
        u = hb[br * 128 + (((c2 >> 2) ^ 7) << 2) + (c2 & 3)]; }
    }
    bnd[pi2] = u;
  }
  __syncthreads();   // GEMM1 LDS reads + bnd reads done

  // ---- agg in place (thread owns column c2 of its 2 patches) ----
#pragma unroll
  for (int pi2 = 0; pi2 < 2; ++pi2) {
    int pi = pg * 2 + pi2;
    int pr = pi * 16;
    int hp = ((g0 + pi) % NPATCH) != 0;
    float vlo[16], vhi[16];
#pragma unroll
    for (int j = 0; j < 16; ++j) {
      uint32 u = hb[(pr + j) * 128 + (((c2 >> 2) ^ (j & 7)) << 2) + (c2 & 3)];
      vlo[j] = lof(u); vhi[j] = hif(u);
    }
    float blo = lof(bnd[pi2]), bhi = hif(bnd[pi2]);
#pragma unroll
    for (int j = 0; j < 16; ++j) {
      const int a = (j - WIN < 0) ? 0 : j - WIN;
      const int b = (j + WIN > 15) ? 15 : j + WIN;
      float slo = 0.f, shi = 0.f;
#pragma unroll
      for (int i = 0; i < 16; ++i)
        if (i >= a && i <= b && i != j) { slo += vlo[i]; shi += vhi[i]; }
      float deg = (float)((j < WIN ? j : WIN) + (15 - j < WIN ? 15 - j : WIN));
      if (j == 0 && hp) { slo += blo; shi += bhi; deg += 1.f; }
      float inv = 1.f / deg;
      hb[(pr + j) * 128 + (((c2 >> 2) ^ (j & 7)) << 2) + (c2 & 3)] = packbf(slo * inv, shi * inv);
    }
  }
  __syncthreads();

  // ---- GEMM2: acc += agg @ Wa^T ----
  __builtin_amdgcn_s_setprio(1);
#pragma unroll
  for (int ks = 0; ks < 8; ++ks) {
    bf16x8 af = *(const bf16x8*)&hb[(rowbase + lr) * 128 + (((ks * 4 + lg) ^ (lr & 7)) << 2)];
#pragma unroll
    for (int nt = 0; nt < 16; ++nt) {
      bf16x8 wf = *(const bf16x8*)(waB + nt * 16 * HID + ks * 32);
      acc[nt] = MFMA_BF16(af, wf, acc[nt], 0, 0, 0);
    }
  }
  __builtin_amdgcn_s_setprio(0);

  // ---- bias + in-register LN stats ----
#pragma unroll
  for (int nt = 0; nt < 16; ++nt) {
    float bv = bias[nt * 16 + lr];
    acc[nt][0] += bv; acc[nt][1] += bv; acc[nt][2] += bv; acc[nt][3] += bv;
  }
  float mean[4], rstd[4];
#pragma unroll
  for (int r = 0; r < 4; ++r) {
    float s = 0.f, s2 = 0.f;
#pragma unroll
    for (int nt = 0; nt < 16; ++nt) { float v = acc[nt][r]; s += v; s2 += v * v; }
    s += __shfl_xor(s, 1); s2 += __shfl_xor(s2, 1);
    s += __shfl_xor(s, 2); s2 += __shfl_xor(s2, 2);
    s += __shfl_xor(s, 4); s2 += __shfl_xor(s2, 4);
    s += __shfl_xor(s, 8); s2 += __shfl_xor(s2, 8);
    mean[r] = s * (1.f / HID);
    rstd[r] = rsqrtf(s2 * (1.f / HID) - mean[r] * mean[r] + 1e-5f);
  }

  // ---- epilogue: LN + ReLU + residual(global) -> swizzled global out ----
  float glv[16], blv[16];
#pragma unroll
  for (int nt = 0; nt < 16; ++nt) { glv[nt] = lng[nt * 16 + lr]; blv[nt] = lnb[nt * 16 + lr]; }
  const u16* hin16 = (const u16*)hin;
  u16* hout16 = (u16*)hout;
#pragma unroll
  for (int r = 0; r < 4; ++r) {
    int rowL = rowbase + lg * 4 + r;
    size_t node = nbase + rowL;
    int r7 = rowL & 7;
#pragma unroll
    for (int nt = 0; nt < 16; ++nt) {
      float v = (acc[nt][r] - mean[r]) * rstd[r] * glv[nt] + blv[nt];
      v = v > 0.f ? v : 0.f;
      size_t a16 = node * 256 + (size_t)((((nt * 2 + (lr >> 3)) ^ r7) << 3) + (lr & 7));
      u16 hraw = hin16[a16];
      v += __bfloat162float(*(const bf16*)&hraw);
      bf16 x = __float2bfloat16(v);
      hout16[a16] = *(const u16*)&x;
    }
  }
}

// -------- LAST SAGE layer (BP=4, proven R14 structure) --------
template<int LAST>
__global__ __launch_bounds__(256, 2) void sage_mfma(
    const bf16* __restrict__ hin,
    const bf16* __restrict__ Wa, const bf16* __restrict__ Wr,
    const float* __restrict__ bias,
    const float* __restrict__ lng, const float* __restrict__ lnb,
    bf16* __restrict__ hout,
    void* __restrict__ dout, const int* __restrict__ flag) {
  int t = threadIdx.x;
  int w = t >> 6, l = t & 63, lr = l & 15, lg = l >> 4;
  int g0 = blockIdx.x * 4;
  size_t nbase = (size_t)g0 * PL;
  __shared__ uint32 h32[64 * 128];
  __shared__ uint32 a32[64 * 128];
  float* mvp = (float*)h32;
  const uint32* hinw = (const uint32*)hin;

  int colbase = w * 64;
  const bf16* waB = Wa + (colbase + lr) * HID + lg * 8;
  const bf16* wrB = Wr + (colbase + lr) * HID + lg * 8;
  bf16x8 wa0[2][8], wr0[2][8];
#pragma unroll
  for (int nt = 0; nt < 2; ++nt)
#pragma unroll
    for (int ks = 0; ks < 8; ++ks) {
      wa0[nt][ks] = *(const bf16x8*)(waB + nt * 16 * HID + ks * 32);
      wr0[nt][ks] = *(const bf16x8*)(wrB + nt * 16 * HID + ks * 32);
    }

  const uint32* hgw = hinw + nbase * 128;
#pragma unroll
  for (int it = 0; it < 8; ++it) {
    int off = (it * 4 + w) * 256;
    gl_lds16(hgw + off + (l << 2), &h32[off]);
  }
  __syncthreads();

  {
    int c2 = t & 127, Ph = t >> 7;
#pragma unroll
    for (int pi = 0; pi < 2; ++pi) {
      int pp = Ph + pi * 2;
      int pr = pp * 16;
      int hp = ((g0 + pp) % NPATCH) != 0;
      float vlo[16], vhi[16];
#pragma unroll
      for (int j = 0; j < 16; ++j) {
        uint32 u = h32[(pr + j) * 128 + (((c2 >> 2) ^ (j & 7)) << 2) + (c2 & 3)];
        vlo[j] = lof(u); vhi[j] = hif(u);
      }
      float blo = 0.f, bhi = 0.f;
      if (hp) {
        uint32 u;
        if (pp == 0) u = hinw[(nbase - 1) * 128 + (((c2 >> 2) ^ 7) << 2) + (c2 & 3)];
        else { int br = pr - 1;
          u = h32[br * 128 + (((c2 >> 2) ^ (br & 7)) << 2) + (c2 & 3)]; }
        blo = lof(u); bhi = hif(u);
      }
#pragma unroll
      for (int j = 0; j < 16; ++j) {
        const int a = (j - WIN < 0) ? 0 : j - WIN;
        const int b = (j + WIN > 15) ? 15 : j + WIN;
        float slo = 0.f, shi = 0.f;
#pragma unroll
        for (int i = 0; i < 16; ++i)
          if (i >= a && i <= b && i != j) { slo += vlo[i]; shi += vhi[i]; }
        float deg = (float)((j < WIN ? j : WIN) + (15 - j < WIN ? 15 - j : WIN));
        if (j == 0 && hp) { slo += blo; shi += bhi; deg += 1.f; }
        float inv = 1.f / deg;
        a32[(pr + j) * 128 + (((c2 >> 2) ^ (j & 7)) << 2) + (c2 & 3)] = packbf(slo * inv, shi * inv);
      }
    }
  }
  __syncthreads();

  f32x4 acc[4][4];
#pragma unroll
  for (int m = 0; m < 4; ++m)
#pragma unroll
    for (int n = 0; n < 4; ++n) acc[m][n] = (f32x4){0.f, 0.f, 0.f, 0.f};
  __builtin_amdgcn_s_setprio(1);
#pragma unroll
  for (int ks = 0; ks < 8; ++ks) {
    bf16x8 wa1[2], wr1[2];
#pragma unroll
    for (int nt = 0; nt < 2; ++nt) {
      wa1[nt] = *(const bf16x8*)(waB + (nt + 2) * 16 * HID + ks * 32);
      wr1[nt] = *(const bf16x8*)(wrB + (nt + 2) * 16 * HID + ks * 32);
    }
#pragma unroll
    for (int m = 0; m < 4; ++m) {
      int idx = (m * 16 + lr) * 128 + (((ks * 4 + lg) ^ (lr & 7)) << 2);
      bf16x8 af = *(const bf16x8*)&a32[idx];
      bf16x8 hf = *(const bf16x8*)&h32[idx];
      acc[m][0] = MFMA_BF16(af, wa0[0][ks], acc[m][0], 0, 0, 0);
      acc[m][0] = MFMA_BF16(hf, wr0[0][ks], acc[m][0], 0, 0, 0);
      acc[m][1] = MFMA_BF16(af, wa0[1][ks], acc[m][1], 0, 0, 0);
      acc[m][1] = MFMA_BF16(hf, wr0[1][ks], acc[m][1], 0, 0, 0);
      acc[m][2] = MFMA_BF16(af, wa1[0],     acc[m][2], 0, 0, 0);
      acc[m][2] = MFMA_BF16(hf, wr1[0],     acc[m][2], 0, 0, 0);
      acc[m][3] = MFMA_BF16(af, wa1[1],     acc[m][3], 0, 0, 0);
      acc[m][3] = MFMA_BF16(hf, wr1[1],     acc[m][3], 0, 0, 0);
    }
  }
  __builtin_amdgcn_s_setprio(0);
#pragma unroll
  for (int nt = 0; nt < 4; ++nt) {
    float bv = bias[colbase + nt * 16 + lr];
#pragma unroll
    for (int m = 0; m < 4; ++m) {
      acc[m][nt][0] += bv; acc[m][nt][1] += bv; acc[m][nt][2] += bv; acc[m][nt][3] += bv;
    }
  }
  __syncthreads();

#pragma unroll
  for (int m = 0; m < 4; ++m)
#pragma unroll
    for (int nt = 0; nt < 4; ++nt) {
      int col = colbase + nt * 16 + lr;
#pragma unroll
      for (int r = 0; r < 4; ++r) {
        int row = m * 16 + lg * 4 + r;
        int i16 = row * 256 + (((col >> 3) ^ (row & 7)) << 3) + (col & 7);
        bf16 x = __float2bfloat16(acc[m][nt][r]);
        ((u16*)a32)[i16] = *(const u16*)&x;
      }
    }
  __syncthreads();

  {
    int row = t >> 2, q = t & 3;
    float s = 0.f, s2 = 0.f;
#pragma unroll
    for (int i = 0; i < 32; ++i) {
      int d = q * 32 + i;
      uint32 u = a32[row * 128 + (((d >> 2) ^ (row & 7)) << 2) + (d & 3)];
      float a = lof(u), b = hif(u);
      s += a + b; s2 += a * a + b * b;
    }
    s += __shfl_xor(s, 1); s2 += __shfl_xor(s2, 1);
    s += __shfl_xor(s, 2); s2 += __shfl_xor(s2, 2);
    if (q == 0) { float mean = s * (1.f / HID);
      mvp[row * 2] = mean;
      mvp[row * 2 + 1] = rsqrtf(s2 * (1.f / HID) - mean * mean + 1e-5f); }
  }
  __syncthreads();

  {
    int c2 = t & 127, prt = t >> 7;
    float gl0 = lng[c2 * 2], gl1 = lng[c2 * 2 + 1];
    float bl0 = lnb[c2 * 2], bl1 = lnb[c2 * 2 + 1];
    uint32* outw = nullptr;
    if constexpr (!LAST) outw = (uint32*)hout + nbase * 128;
    const uint32* inw = hinw + nbase * 128;
    int fl = 0;
    if constexpr (LAST) fl = *flag;
#pragma unroll
    for (int pi = 0; pi < 2; ++pi) {
      float sga = 0.f, sgb = 0.f;
#pragma unroll
      for (int i = 0; i < 16; ++i) {
        int row = prt * 32 + pi * 16 + i;
        int pidx = row * 128 + (((c2 >> 2) ^ (row & 7)) << 2) + (c2 & 3);
        uint32 u = a32[pidx];
        float mean = mvp[row * 2], rstd = mvp[row * 2 + 1];
        float a = (lof(u) - mean) * rstd * gl0 + bl0; a = a > 0.f ? a : 0.f;
        float b_ = (hif(u) - mean) * rstd * gl1 + bl1; b_ = b_ > 0.f ? b_ : 0.f;
        uint32 hu = inw[pidx];
        a += lof(hu); b_ += hif(hu);
        if constexpr (!LAST) {
          outw[pidx] = packbf(a, b_);
        } else {
          sga += a; sgb += b_;
          if (fl) {
            size_t ei = (size_t)EMB_EOFF + (nbase + row) * 256 + (size_t)c2 * 2;
            *(float2*)&((float*)dout)[ei] = make_float2(a, b_);
          } else {
            ((uint32*)dout)[(EMB_EOFF >> 1) + (nbase + row) * 128 + c2] = packbf(a, b_);
          }
        }
      }
      if constexpr (LAST) {
        float ga = sga * (1.f / PL), gb = sgb * (1.f / PL);
        int gidx = g0 + prt * 2 + pi;
        if (fl) {
          size_t gi = (size_t)GF_EOFF + (size_t)gidx * 256 + (size_t)c2 * 2;
          *(float2*)&((float*)dout)[gi] = make_float2(ga, gb);
        } else {
          ((uint32*)dout)[(GF_EOFF >> 1) + gidx * 128 + c2] = packbf(ga, gb);
        }
      }
    }
  }
}

// -------- head: MLP + LN + ReLU + logits (gf already in d_out, linear) --------
__global__ __launch_bounds__(256) void head_kernel(
    const void* __restrict__ gin, const float* __restrict__ P,
    void* __restrict__ dout, const int* __restrict__ flag) {
  int g = blockIdx.x, f = threadIdx.x;
  int fl = *flag;
  __shared__ float gf_s[HID];
  __shared__ float z_s[HID];
  __shared__ float ps[4], ps2[4];
  __shared__ float mr[2];
  gf_s[f] = fl ? ((const float*)gin)[(size_t)GF_EOFF + (size_t)g * HID + f]
               : b2f(((const bf16*)gin)[(size_t)GF_EOFF + (size_t)g * HID + f]);
  __syncthreads();
  float acc = P[CB1_OFF + f];
  for (int k = 0; k < HID; k += 4) {
    const float4 gv = *(const float4*)(&gf_s[k]);
    acc = fmaf(gv.x, P[W1T_OFF + (k + 0) * HID + f], acc);
    acc = fmaf(gv.y, P[W1T_OFF + (k + 1) * HID + f], acc);
    acc = fmaf(gv.z, P[W1T_OFF + (k + 2) * HID + f], acc);
    acc = fmaf(gv.w, P[W1T_OFF + (k + 3) * HID + f], acc);
  }
  float s1 = acc, s2 = acc * acc;
#pragma unroll
  for (int m = 32; m >= 1; m >>= 1) { s1 += __shfl_xor(s1, m); s2 += __shfl_xor(s2, m); }
  int wid = f >> 6, lane = f & 63;
  if (lane == 0) { ps[wid] = s1; ps2[wid] = s2; }
  __syncthreads();
  if (f == 0) {
    float S = ps[0] + ps[1] + ps[2] + ps[3];
    float S2 = ps2[0] + ps2[1] + ps2[2] + ps2[3];
    float mean = S * (1.f / HID);
    mr[0] = mean; mr[1] = rsqrtf(S2 * (1.f / HID) - mean * mean + 1e-5f);
  }
  __syncthreads();
  float z = (acc - mr[0]) * mr[1] * P[CLNS_OFF + f] + P[CLNB_OFF + f];
  z = z > 0.f ? z : 0.f;
  z_s[f] = z;
  __syncthreads();
  {
    int cls = f >> 5, lane2 = f & 31;
    float a = 0.f;
    for (int k = lane2; k < HID; k += 32)
      a = fmaf(z_s[k], P[CW2_OFF + cls * HID + k], a);
    a += __shfl_xor(a, 16); a += __shfl_xor(a, 8);
    a += __shfl_xor(a, 4);  a += __shfl_xor(a, 2); a += __shfl_xor(a, 1);
    if (lane2 == 0) {
      a += P[CB2_OFF + cls];
      size_t ei = (size_t)g * NCLS + cls;
      if (fl) ((float*)dout)[ei] = a; else ((bf16*)dout)[ei] = __float2bfloat16(a);
    }
  }
}

extern "C" void kernel_launch(void* const* d_in, const int* in_sizes, int n_in,
                              void* d_out, int out_size, void* d_ws, size_t ws_size,
                              hipStream_t stream) {
  char* ws = (char*)d_ws;
  int*   flag = (int*)ws;
  float* P    = (float*)(ws + P_BYTE_OFF);
  bf16*  WB   = (bf16*)(ws + WB_BYTE_OFF);
  bf16*  A    = (bf16*)(ws + A_BYTE_OFF);                 // in workspace
  bf16*  B    = (bf16*)((char*)d_out + B_BYTE_OFF);       // in d_out (emb region)

  detect_kernel<<<1, 256, 0, stream>>>((const u16*)d_in[0], flag);
  convert_all<<<(CVT_TOTAL + WB_TOTAL + 255) / 256, 256, 0, stream>>>(
      flag, d_in[0], d_in[3], d_in[4], d_in[5], d_in[8],
      d_in[9], d_in[10], d_in[11], d_in[12], d_in[13], d_in[14], d_in[15], d_in[16],
      d_in[6], d_in[7], P, WB);

  // layer0->A, bp8 sage1 A->B, bp8 sage2 B->A, BP4 sage3 A->d_out
  layer0_kernel<<<NG, 256, 0, stream>>>(P, A);
  sage_bp8<<<NG / 8, 512, 0, stream>>>(A, WB, WB + 65536,
      P + BLIN_OFF, P + LNS_OFF + HID, P + LNB_OFF + HID, B);
  sage_bp8<<<NG / 8, 512, 0, stream>>>(B, WB + 131072, WB + 131072 + 65536,
      P + BLIN_OFF + HID, P + LNS_OFF + 2 * HID, P + LNB_OFF + 2 * HID, A);
  sage_mfma<1><<<NG / 4, 256, 0, stream>>>(A, WB + 262144, WB + 262144 + 65536,
      P + BLIN_OFF + 2 * HID, P + LNS_OFF + 3 * HID, P + LNB_OFF + 3 * HID, nullptr, d_out, flag);
  head_kernel<<<NG, 256, 0, stream>>>(d_out, P, d_out, flag);
}

// Round 17
// 225.274 us; speedup vs baseline: 1.8726x; 1.8726x over previous
//
#include <hip/hip_runtime.h>
#include <hip/hip_bf16.h>

typedef __hip_bfloat16 bf16;
typedef unsigned short u16;
typedef unsigned int uint32;
typedef __attribute__((ext_vector_type(8))) short bf16x8;
typedef __attribute__((ext_vector_type(4))) float f32x4;

#define BATCH   128
#define LSIG    128
#define PL      16
#define ST      4
#define WIN     4
#define NPATCH  29
#define NG      (BATCH * NPATCH)   // 3712
#define NNODE   (NG * PL)          // 59392
#define HID     256
#define NCLS    8

// f32 param workspace layout (element offsets)
#define IQ_OFF    0
#define W0A_OFF   32768
#define W0R_OFF   33280
#define B0_OFF    33792
#define BLIN_OFF  34048
#define LNS_OFF   34816
#define LNB_OFF   35840
#define W1T_OFF   36864
#define CB1_OFF   102400
#define CLNS_OFF  102656
#define CLNB_OFF  102912
#define CW2_OFF   103168
#define CB2_OFF   105216
#define CVT_TOTAL 105224
#define WB_TOTAL  393216

#define P_BYTE_OFF   4096
#define WB_BYTE_OFF  425984           // bf16 sage weights: 3 layers x (Wa|Wr) x 65536
#define A_BYTE_OFF   1216512          // bf16 activation buffer in ws (30.4 MB)
#define B_BYTE_OFF   1959936          // bf16 scratch window inside d_out (= emb region)
#define GF_EOFF      (NG * NCLS)                  // 29696
#define EMB_EOFF     (NG * NCLS + NG * HID)       // 979968

#define MFMA_BF16 __builtin_amdgcn_mfma_f32_16x16x32_bf16

__device__ __forceinline__ float b2f(bf16 x) { return __bfloat162float(x); }
__device__ __forceinline__ float lof(uint32 u) { return __uint_as_float(u << 16); }
__device__ __forceinline__ float hif(uint32 u) { return __uint_as_float(u & 0xFFFF0000u); }
__device__ __forceinline__ uint32 packbf(float a, float b) {
  bf16 r0 = __float2bfloat16(a), r1 = __float2bfloat16(b);
  return ((uint32)(*(const u16*)&r1) << 16) | (uint32)(*(const u16*)&r0);
}
__device__ __forceinline__ float ldmix(const void* p, size_t i, int fl) {
  return fl ? ((const float*)p)[i] : __bfloat162float(((const bf16*)p)[i]);
}
// async 16B/lane global->LDS (wave-uniform LDS base, per-lane global addr)
__device__ __forceinline__ void gl_lds16(const uint32* gsrc, uint32* ldst) {
  __builtin_amdgcn_global_load_lds(
      (const __attribute__((address_space(1))) uint32*)gsrc,
      (__attribute__((address_space(3))) uint32*)ldst, 16, 0, 0);
}

// -------- dtype detector --------
__global__ __launch_bounds__(256) void detect_kernel(const u16* __restrict__ iq, int* flag) {
  __shared__ int sbig, snz;
  int t = threadIdx.x;
  if (t == 0) { sbig = 0; snz = 0; }
  __syncthreads();
  int big = 0, nz = 0;
  for (int e = t; e < 16384; e += 256) {
    u16 u = iq[2 * e];
    int ex = (u >> 7) & 0xFF;
    if (ex >= 0xC0) big++;
    if (u != 0) nz++;
  }
  atomicAdd(&sbig, big); atomicAdd(&snz, nz);
  __syncthreads();
  if (t == 0) *flag = (sbig > 4 || snz < 100) ? 1 : 0;   // 1 = f32 inputs
}

// -------- all input conversions: params -> f32 P, sage W -> bf16 WB --------
__global__ __launch_bounds__(256) void convert_all(
    const int* __restrict__ flag,
    const void* iq, const void* w0a, const void* w0r, const void* b0,
    const void* blin, const void* lns, const void* lnb,
    const void* cw1, const void* cb1, const void* clns, const void* clnb,
    const void* cw2, const void* cb2,
    const void* wag, const void* wro,
    float* __restrict__ P, bf16* __restrict__ WB) {
  int idx = blockIdx.x * 256 + threadIdx.x;
  int fl = *flag;
  if (idx < CVT_TOTAL) {
    float v;
    if (idx < W0A_OFF)        v = ldmix(iq,  idx, fl);
    else if (idx < W0R_OFF)   v = ldmix(w0a, idx - W0A_OFF, fl);
    else if (idx < B0_OFF)    v = ldmix(w0r, idx - W0R_OFF, fl);
    else if (idx < BLIN_OFF)  v = ldmix(b0,  idx - B0_OFF, fl);
    else if (idx < LNS_OFF)   v = ldmix(blin, idx - BLIN_OFF, fl);
    else if (idx < LNB_OFF)   v = ldmix(lns, idx - LNS_OFF, fl);
    else if (idx < W1T_OFF)   v = ldmix(lnb, idx - LNB_OFF, fl);
    else if (idx < CB1_OFF) { int t2 = idx - W1T_OFF;
      v = ldmix(cw1, (t2 & 255) * 256 + (t2 >> 8), fl); }
    else if (idx < CLNS_OFF)  v = ldmix(cb1, idx - CB1_OFF, fl);
    else if (idx < CLNB_OFF)  v = ldmix(clns, idx - CLNS_OFF, fl);
    else if (idx < CW2_OFF)   v = ldmix(clnb, idx - CLNB_OFF, fl);
    else if (idx < CB2_OFF)   v = ldmix(cw2, idx - CW2_OFF, fl);
    else                      v = ldmix(cb2, idx - CB2_OFF, fl);
    P[idx] = v;
  } else if (idx < CVT_TOTAL + WB_TOTAL) {
    int k = idx - CVT_TOTAL;
    int l = k >> 17, m = (k >> 16) & 1, r = k & 65535;
    const void* src = m ? wro : wag;
    WB[k] = __float2bfloat16(ldmix(src, l * 65536 + r, fl));
  }
}

// -------- layer 0: patch extract + SAGE(2->256) + LN + ReLU --------
// Output written in SWIZZLED global layout (16B slot ^= row&7) so sage staging
// can be a pure linear global_load_lds copy.
__global__ __launch_bounds__(256) void layer0_kernel(
    const float* __restrict__ P, bf16* __restrict__ hout) {
  int g = blockIdx.x, f = threadIdx.x;
  int b = g / NPATCH, p = g % NPATCH;
  __shared__ float x_s[PL][2];
  __shared__ float xp_s[2];
  __shared__ float agg_s[PL][2];
  __shared__ float o_s[PL][HID];
  __shared__ float mv_s[PL][2];
  if (f < 32) { int j = f & 15, c = f >> 4;
    x_s[j][c] = P[IQ_OFF + (b * 2 + c) * LSIG + p * ST + j]; }
  if (f < 2) xp_s[f] = (p > 0) ? P[IQ_OFF + (b * 2 + f) * LSIG + (p - 1) * ST + PL - 1] : 0.f;
  __syncthreads();
  if (f < 32) { int j = f & 15, c = f >> 4;
    float s = 0.f;
    int lo = j - WIN < 0 ? 0 : j - WIN, hi = j + WIN > 15 ? 15 : j + WIN;
    for (int i = lo; i <= hi; ++i) if (i != j) s += x_s[i][c];
    int deg = (j < WIN ? j : WIN) + ((15 - j) < WIN ? (15 - j) : WIN);
    if (j == 0 && p > 0) { s += xp_s[c]; deg += 1; }
    agg_s[j][c] = s / (float)deg;
  }
  __syncthreads();
  float wa0 = P[W0A_OFF + f * 2], wa1 = P[W0A_OFF + f * 2 + 1];
  float wr0 = P[W0R_OFF + f * 2], wr1 = P[W0R_OFF + f * 2 + 1];
  float bb = P[B0_OFF + f];
#pragma unroll
  for (int j = 0; j < PL; ++j)
    o_s[j][f] = agg_s[j][0] * wa0 + agg_s[j][1] * wa1 + x_s[j][0] * wr0 + x_s[j][1] * wr1 + bb;
  __syncthreads();
  { int j = f >> 4, q = f & 15;
    float s = 0.f, s2 = 0.f;
#pragma unroll
    for (int i = 0; i < 16; ++i) { float v = o_s[j][q + 16 * i]; s += v; s2 += v * v; }
#pragma unroll
    for (int m = 8; m >= 1; m >>= 1) { s += __shfl_xor(s, m); s2 += __shfl_xor(s2, m); }
    if (q == 0) { float mean = s * (1.f / HID);
      float var = s2 * (1.f / HID) - mean * mean;
      mv_s[j][0] = mean; mv_s[j][1] = rsqrtf(var + 1e-5f); }
  }
  __syncthreads();
  float gl = P[LNS_OFF + f], bl = P[LNB_OFF + f];
#pragma unroll
  for (int j = 0; j < PL; ++j) {
    float v = (o_s[j][f] - mv_s[j][0]) * mv_s[j][1] * gl + bl;
    v = v > 0.f ? v : 0.f;
    bf16 x = __float2bfloat16(v);
    // swizzled: node n=g*PL+j, slot (f>>3) ^ (j&7), u16-in-slot f&7
    ((u16*)hout)[(size_t)(g * PL + j) * 256 + ((((f >> 3) ^ (j & 7))) << 3) + (f & 7)] = *(const u16*)&x;
  }
}

// -------- SAGE layer 256->256 via MFMA + LN + ReLU + residual --------
// Inputs/outputs in swizzled global layout (except LAST emb/gf = linear).
// Stage = linear 32KB copy via global_load_lds (async, no VGPR round trip).
template<int LAST>
__global__ __launch_bounds__(256, 2) void sage_mfma(
    const bf16* __restrict__ hin,
    const bf16* __restrict__ Wa, const bf16* __restrict__ Wr,
    const float* __restrict__ bias,
    const float* __restrict__ lng, const float* __restrict__ lnb,
    bf16* __restrict__ hout,
    void* __restrict__ dout, const int* __restrict__ flag) {
  int t = threadIdx.x;
  int w = t >> 6, l = t & 63, lr = l & 15, lg = l >> 4;
  int g0 = blockIdx.x * 4;
  size_t nbase = (size_t)g0 * PL;
  __shared__ uint32 h32[64 * 128];
  __shared__ uint32 a32[64 * 128];
  float* mvp = (float*)h32;                 // aliased after h32 is dead
  const uint32* hinw = (const uint32*)hin;

  // ---- B preload (nt 0,1; all ks): latency hides under stage+agg ----
  int colbase = w * 64;
  const bf16* waB = Wa + (colbase + lr) * HID + lg * 8;
  const bf16* wrB = Wr + (colbase + lr) * HID + lg * 8;
  bf16x8 wa0[2][8], wr0[2][8];
#pragma unroll
  for (int nt = 0; nt < 2; ++nt)
#pragma unroll
    for (int ks = 0; ks < 8; ++ks) {
      wa0[nt][ks] = *(const bf16x8*)(waB + nt * 16 * HID + ks * 32);
      wr0[nt][ks] = *(const bf16x8*)(wrB + nt * 16 * HID + ks * 32);
    }

  // ---- stage h: pure linear copy (global already swizzled) ----
  const uint32* hgw = hinw + nbase * 128;
#pragma unroll
  for (int it = 0; it < 8; ++it) {
    int off = (it * 4 + w) * 256;          // dwords; wave-uniform LDS base
    gl_lds16(hgw + off + (l << 2), &h32[off]);
  }
  __syncthreads();

  // ---- agg (windowed mean) : thread = (col-pair c2, patch-half) ----
  {
    int c2 = t & 127, Ph = t >> 7;
#pragma unroll
    for (int pi = 0; pi < 2; ++pi) {
      int pp = Ph + pi * 2;
      int pr = pp * 16;
      int hp = ((g0 + pp) % NPATCH) != 0;
      float vlo[16], vhi[16];
#pragma unroll
      for (int j = 0; j < 16; ++j) {
        uint32 u = h32[(pr + j) * 128 + (((c2 >> 2) ^ (j & 7)) << 2) + (c2 & 3)];
        vlo[j] = lof(u); vhi[j] = hif(u);
      }
      float blo = 0.f, bhi = 0.f;
      if (hp) {
        uint32 u;
        if (pp == 0) u = hinw[(nbase - 1) * 128 + (((c2 >> 2) ^ 7) << 2) + (c2 & 3)];
        else { int br = pr - 1;
          u = h32[br * 128 + (((c2 >> 2) ^ (br & 7)) << 2) + (c2 & 3)]; }
        blo = lof(u); bhi = hif(u);
      }
#pragma unroll
      for (int j = 0; j < 16; ++j) {
        const int a = (j - WIN < 0) ? 0 : j - WIN;
        const int b = (j + WIN > 15) ? 15 : j + WIN;
        float slo = 0.f, shi = 0.f;
#pragma unroll
        for (int i = 0; i < 16; ++i)
          if (i >= a && i <= b && i != j) { slo += vlo[i]; shi += vhi[i]; }
        float deg = (float)((j < WIN ? j : WIN) + (15 - j < WIN ? 15 - j : WIN));
        if (j == 0 && hp) { slo += blo; shi += bhi; deg += 1.f; }
        float inv = 1.f / deg;
        a32[(pr + j) * 128 + (((c2 >> 2) ^ (j & 7)) << 2) + (c2 & 3)] = packbf(slo * inv, shi * inv);
      }
    }
  }
  __syncthreads();

  // ---- MFMA GEMM: out = agg@Wa^T + h@Wr^T ----
  f32x4 acc[4][4];
#pragma unroll
  for (int m = 0; m < 4; ++m)
#pragma unroll
    for (int n = 0; n < 4; ++n) acc[m][n] = (f32x4){0.f, 0.f, 0.f, 0.f};
  __builtin_amdgcn_s_setprio(1);
#pragma unroll
  for (int ks = 0; ks < 8; ++ks) {
    bf16x8 wa1[2], wr1[2];
#pragma unroll
    for (int nt = 0; nt < 2; ++nt) {
      wa1[nt] = *(const bf16x8*)(waB + (nt + 2) * 16 * HID + ks * 32);
      wr1[nt] = *(const bf16x8*)(wrB + (nt + 2) * 16 * HID + ks * 32);
    }
#pragma unroll
    for (int m = 0; m < 4; ++m) {
      int idx = (m * 16 + lr) * 128 + (((ks * 4 + lg) ^ (lr & 7)) << 2);
      bf16x8 af = *(const bf16x8*)&a32[idx];
      bf16x8 hf = *(const bf16x8*)&h32[idx];
      acc[m][0] = MFMA_BF16(af, wa0[0][ks], acc[m][0], 0, 0, 0);
      acc[m][0] = MFMA_BF16(hf, wr0[0][ks], acc[m][0], 0, 0, 0);
      acc[m][1] = MFMA_BF16(af, wa0[1][ks], acc[m][1], 0, 0, 0);
      acc[m][1] = MFMA_BF16(hf, wr0[1][ks], acc[m][1], 0, 0, 0);
      acc[m][2] = MFMA_BF16(af, wa1[0],     acc[m][2], 0, 0, 0);
      acc[m][2] = MFMA_BF16(hf, wr1[0],     acc[m][2], 0, 0, 0);
      acc[m][3] = MFMA_BF16(af, wa1[1],     acc[m][3], 0, 0, 0);
      acc[m][3] = MFMA_BF16(hf, wr1[1],     acc[m][3], 0, 0, 0);
    }
  }
  __builtin_amdgcn_s_setprio(0);
  // bias (per output column)
#pragma unroll
  for (int nt = 0; nt < 4; ++nt) {
    float bv = bias[colbase + nt * 16 + lr];
#pragma unroll
    for (int m = 0; m < 4; ++m) {
      acc[m][nt][0] += bv; acc[m][nt][1] += bv; acc[m][nt][2] += bv; acc[m][nt][3] += bv;
    }
  }
  __syncthreads();                 // all A-frag reads done

  // ---- store o into a32 (D layout: col=lane&15, row=(lane>>4)*4+reg) ----
#pragma unroll
  for (int m = 0; m < 4; ++m)
#pragma unroll
    for (int nt = 0; nt < 4; ++nt) {
      int col = colbase + nt * 16 + lr;
#pragma unroll
      for (int r = 0; r < 4; ++r) {
        int row = m * 16 + lg * 4 + r;
        int i16 = row * 256 + (((col >> 3) ^ (row & 7)) << 3) + (col & 7);
        bf16 x = __float2bfloat16(acc[m][nt][r]);
        ((u16*)a32)[i16] = *(const u16*)&x;
      }
    }
  __syncthreads();

  // ---- LN stats: 4 threads per row; mean/rstd -> mvp (aliases dead h32) ----
  {
    int row = t >> 2, q = t & 3;
    float s = 0.f, s2 = 0.f;
#pragma unroll
    for (int i = 0; i < 32; ++i) {
      int d = q * 32 + i;
      uint32 u = a32[row * 128 + (((d >> 2) ^ (row & 7)) << 2) + (d & 3)];
      float a = lof(u), b = hif(u);
      s += a + b; s2 += a * a + b * b;
    }
    s += __shfl_xor(s, 1); s2 += __shfl_xor(s2, 1);
    s += __shfl_xor(s, 2); s2 += __shfl_xor(s2, 2);
    if (q == 0) { float mean = s * (1.f / HID);
      mvp[row * 2] = mean;
      mvp[row * 2 + 1] = rsqrtf(s2 * (1.f / HID) - mean * mean + 1e-5f); }
  }
  __syncthreads();

  // ---- epilogue: LN + ReLU + residual; non-LAST writes SWIZZLED h ----
  {
    int c2 = t & 127, prt = t >> 7;
    float gl0 = lng[c2 * 2], gl1 = lng[c2 * 2 + 1];
    float bl0 = lnb[c2 * 2], bl1 = lnb[c2 * 2 + 1];
    uint32* outw = nullptr;
    if constexpr (!LAST) outw = (uint32*)hout + nbase * 128;
    const uint32* inw = hinw + nbase * 128;
    int fl = 0;
    if constexpr (LAST) fl = *flag;
#pragma unroll
    for (int pi = 0; pi < 2; ++pi) {
      float sga = 0.f, sgb = 0.f;
#pragma unroll
      for (int i = 0; i < 16; ++i) {
        int row = prt * 32 + pi * 16 + i;
        int pidx = row * 128 + (((c2 >> 2) ^ (row & 7)) << 2) + (c2 & 3);
        uint32 u = a32[pidx];
        float mean = mvp[row * 2], rstd = mvp[row * 2 + 1];
        float a = (lof(u) - mean) * rstd * gl0 + bl0; a = a > 0.f ? a : 0.f;
        float b_ = (hif(u) - mean) * rstd * gl1 + bl1; b_ = b_ > 0.f ? b_ : 0.f;
        uint32 hu = inw[pidx];             // input buffer is swizzled too
        a += lof(hu); b_ += hif(hu);
        if constexpr (!LAST) {
          outw[pidx] = packbf(a, b_);      // keep swizzled layout for next stage
        } else {
          sga += a; sgb += b_;
          if (fl) {
            size_t ei = (size_t)EMB_EOFF + (nbase + row) * 256 + (size_t)c2 * 2;
            *(float2*)&((float*)dout)[ei] = make_float2(a, b_);
          } else {
            ((uint32*)dout)[(EMB_EOFF >> 1) + (nbase + row) * 128 + c2] = packbf(a, b_);
          }
        }
      }
      if constexpr (LAST) {
        float ga = sga * (1.f / PL), gb = sgb * (1.f / PL);
        int gidx = g0 + prt * 2 + pi;
        if (fl) {
          size_t gi = (size_t)GF_EOFF + (size_t)gidx * 256 + (size_t)c2 * 2;
          *(float2*)&((float*)dout)[gi] = make_float2(ga, gb);
        } else {
          ((uint32*)dout)[(GF_EOFF >> 1) + gidx * 128 + c2] = packbf(ga, gb);
        }
      }
    }
  }
}

// -------- head: MLP + LN + ReLU + logits (gf already in d_out, linear) --------
__global__ __launch_bounds__(256) void head_kernel(
    const void* __restrict__ gin, const float* __restrict__ P,
    void* __restrict__ dout, const int* __restrict__ flag) {
  int g = blockIdx.x, f = threadIdx.x;
  int fl = *flag;
  __shared__ float gf_s[HID];
  __shared__ float z_s[HID];
  __shared__ float ps[4], ps2[4];
  __shared__ float mr[2];
  gf_s[f] = fl ? ((const float*)gin)[(size_t)GF_EOFF + (size_t)g * HID + f]
               : b2f(((const bf16*)gin)[(size_t)GF_EOFF + (size_t)g * HID + f]);
  __syncthreads();
  float acc = P[CB1_OFF + f];
  for (int k = 0; k < HID; k += 4) {
    const float4 gv = *(const float4*)(&gf_s[k]);
    acc = fmaf(gv.x, P[W1T_OFF + (k + 0) * HID + f], acc);
    acc = fmaf(gv.y, P[W1T_OFF + (k + 1) * HID + f], acc);
    acc = fmaf(gv.z, P[W1T_OFF + (k + 2) * HID + f], acc);
    acc = fmaf(gv.w, P[W1T_OFF + (k + 3) * HID + f], acc);
  }
  float s1 = acc, s2 = acc * acc;
#pragma unroll
  for (int m = 32; m >= 1; m >>= 1) { s1 += __shfl_xor(s1, m); s2 += __shfl_xor(s2, m); }
  int wid = f >> 6, lane = f & 63;
  if (lane == 0) { ps[wid] = s1; ps2[wid] = s2; }
  __syncthreads();
  if (f == 0) {
    float S = ps[0] + ps[1] + ps[2] + ps[3];
    float S2 = ps2[0] + ps2[1] + ps2[2] + ps2[3];
    float mean = S * (1.f / HID);
    mr[0] = mean; mr[1] = rsqrtf(S2 * (1.f / HID) - mean * mean + 1e-5f);
  }
  __syncthreads();
  float z = (acc - mr[0]) * mr[1] * P[CLNS_OFF + f] + P[CLNB_OFF + f];
  z = z > 0.f ? z : 0.f;
  z_s[f] = z;
  __syncthreads();
  // logits: 32 lanes per class, shuffle-reduced
  {
    int cls = f >> 5, lane2 = f & 31;
    float a = 0.f;
    for (int k = lane2; k < HID; k += 32)
      a = fmaf(z_s[k], P[CW2_OFF + cls * HID + k], a);
    a += __shfl_xor(a, 16); a += __shfl_xor(a, 8);
    a += __shfl_xor(a, 4);  a += __shfl_xor(a, 2); a += __shfl_xor(a, 1);
    if (lane2 == 0) {
      a += P[CB2_OFF + cls];
      size_t ei = (size_t)g * NCLS + cls;
      if (fl) ((float*)dout)[ei] = a; else ((bf16*)dout)[ei] = __float2bfloat16(a);
    }
  }
}

extern "C" void kernel_launch(void* const* d_in, const int* in_sizes, int n_in,
                              void* d_out, int out_size, void* d_ws, size_t ws_size,
                              hipStream_t stream) {
  char* ws = (char*)d_ws;
  int*   flag = (int*)ws;
  float* P    = (float*)(ws + P_BYTE_OFF);
  bf16*  WB   = (bf16*)(ws + WB_BYTE_OFF);
  bf16*  A    = (bf16*)(ws + A_BYTE_OFF);                 // in workspace
  bf16*  B    = (bf16*)((char*)d_out + B_BYTE_OFF);       // in d_out (emb region)

  detect_kernel<<<1, 256, 0, stream>>>((const u16*)d_in[0], flag);
  convert_all<<<(CVT_TOTAL + WB_TOTAL + 255) / 256, 256, 0, stream>>>(
      flag, d_in[0], d_in[3], d_in[4], d_in[5], d_in[8],
      d_in[9], d_in[10], d_in[11], d_in[12], d_in[13], d_in[14], d_in[15], d_in[16],
      d_in[6], d_in[7], P, WB);

  // layer0->A, sage1 A->B, sage2 B->A, sage3 A->d_out (all in/out disjoint)
  layer0_kernel<<<NG, 256, 0, stream>>>(P, A);
  sage_mfma<0><<<NG / 4, 256, 0, stream>>>(A, WB, WB + 65536,
      P + BLIN_OFF, P + LNS_OFF + HID, P + LNB_OFF + HID, B, nullptr, flag);
  sage_mfma<0><<<NG / 4, 256, 0, stream>>>(B, WB + 131072, WB + 131072 + 65536,
      P + BLIN_OFF + HID, P + LNS_OFF + 2 * HID, P + LNB_OFF + 2 * HID, A, nullptr, flag);
  sage_mfma<1><<<NG / 4, 256, 0, stream>>>(A, WB + 262144, WB + 262144 + 65536,
      P + BLIN_OFF + 2 * HID, P + LNS_OFF + 3 * HID, P + LNB_OFF + 3 * HID, nullptr, d_out, flag);
  head_kernel<<<NG, 256, 0, stream>>>(d_out, P, d_out, flag);
}